// Round 1
// baseline (406.388 us; speedup 1.0000x reference)
//
#include <hip/hip_runtime.h>

// OFT rotation: out[n, r*64+c] = sum_k x[n, r*64+k] * R[r][k][c]
// R[r] = I + 2(Q + Q^2 + Q^3 + Q^4), Q skew-symmetric from strict-upper weights.

#define BS 64
#define NW 2016   // 64*63/2
#define LDP 68    // padded LDS row stride (float4-aligned, breaks pow2 bank stride)

// ---------------- Kernel 1: build R (64 blocks, one per rotation block) -------------
// UNCHANGED from previous round: ~10 us, bit-exact vs reference (absmax 0.0).

__device__ __forceinline__ void mm_tile_68(const float (*A)[LDP], const float (*Bm)[LDP],
                                           int r0, int c0, float p[4][4]) {
  // p += A[r0..r0+3][:] * Bm[:][c0..c0+3], K=64, stride LDP
  for (int k = 0; k < 64; k += 4) {
    float4 bv[4], av[4];
#pragma unroll
    for (int u = 0; u < 4; ++u) bv[u] = *(const float4*)&Bm[k + u][c0];
#pragma unroll
    for (int i = 0; i < 4; ++i) av[i] = *(const float4*)&A[r0 + i][k];
#pragma unroll
    for (int u = 0; u < 4; ++u) {
      const float4 b = bv[u];
#pragma unroll
      for (int i = 0; i < 4; ++i) {
        const float a = ((const float*)&av[i])[u];
        p[i][0] += a * b.x;
        p[i][1] += a * b.y;
        p[i][2] += a * b.z;
        p[i][3] += a * b.w;
      }
    }
  }
}

__global__ __launch_bounds__(256) void oft_build_R(const float* __restrict__ w,
                                                   float* __restrict__ Rout) {
  const int r = blockIdx.x;
  const int t = threadIdx.x;
  __shared__ float Q[BS][LDP];
  __shared__ float Pa[BS][LDP];
  __shared__ float Pb[BS][LDP];

  // zero Q (including pad)
  for (int f = t; f < BS * LDP; f += 256) (&Q[0][0])[f] = 0.f;
  __syncthreads();

  // scatter weights: strict upper triangle, row-major order (np.triu_indices(64,1))
  for (int i = t; i < NW; i += 256) {
    int row = 0, rem = i;
    while (rem >= 63 - row) { rem -= 63 - row; ++row; }
    const int col = row + 1 + rem;
    const float v = w[r * NW + i];
    Q[row][col] = v;
    Q[col][row] = -v;
  }
  __syncthreads();

  const int tr = t >> 4, tc = t & 15;
  const int r0 = tr * 4, c0 = tc * 4;

  float acc[4][4];
#pragma unroll
  for (int i = 0; i < 4; ++i)
#pragma unroll
    for (int j = 0; j < 4; ++j)
      acc[i][j] = ((r0 + i) == (c0 + j) ? 1.f : 0.f) + 2.f * Q[r0 + i][c0 + j];

  // P = Q*Q
  float p[4][4] = {};
  mm_tile_68(Q, Q, r0, c0, p);
#pragma unroll
  for (int i = 0; i < 4; ++i)
#pragma unroll
    for (int j = 0; j < 4; ++j) {
      Pa[r0 + i][c0 + j] = p[i][j];
      acc[i][j] += 2.f * p[i][j];
    }
  __syncthreads();

  // P2 = Pa*Q
  float p2[4][4] = {};
  mm_tile_68(Pa, Q, r0, c0, p2);
#pragma unroll
  for (int i = 0; i < 4; ++i)
#pragma unroll
    for (int j = 0; j < 4; ++j) {
      Pb[r0 + i][c0 + j] = p2[i][j];
      acc[i][j] += 2.f * p2[i][j];
    }
  __syncthreads();

  // P3 = Pb*Q (registers only)
  float p3[4][4] = {};
  mm_tile_68(Pb, Q, r0, c0, p3);
#pragma unroll
  for (int i = 0; i < 4; ++i)
#pragma unroll
    for (int j = 0; j < 4; ++j)
      acc[i][j] += 2.f * p3[i][j];

  // write R[r] (row-major 64x64), float4 per row
#pragma unroll
  for (int i = 0; i < 4; ++i) {
    float4 v = make_float4(acc[i][0], acc[i][1], acc[i][2], acc[i][3]);
    *(float4*)&Rout[(size_t)r * 4096 + (size_t)(r0 + i) * 64 + c0] = v;
  }
}

// ---------------- Kernel 2: apply block-diagonal rotation (v2: zero-LDS) -------------
//
// Previous version was LDS-read-throughput bound: 2 B of ds_read per FMA ->
// 4.3 GB of LDS traffic @ ~85 B/cyc/CU = ~82 us (matched measured 80 us).
//
// v2: lane = output column c. Each lane keeps R[r][:, c] in 64 VGPRs (loaded
// once per block, reused over 128 rows). x[n, r*64+k] is wave-uniform ->
// scalar/uniform loads. acc = sum_k x[k] * Rcol[k], two rows per wave in
// flight (two independent FMA chains hide the 4-cyc FMA latency). No LDS at
// all. FMA order per output is ascending k with fma, identical to v1 ->
// results stay bit-identical.

#define ROWS_PER_BLOCK 128
#define ROWS_PER_WAVE 32   // 4 waves * 32 rows = 128

__global__ __launch_bounds__(256) void oft_apply(const float* __restrict__ x,
                                                 const float* __restrict__ R,
                                                 float* __restrict__ out) {
  const int r = blockIdx.x;      // rotation block 0..63
  const int tile = blockIdx.y;   // row tile 0..63 (128 rows each)
  const int lane = threadIdx.x & 63;
  // Force wave-uniformity so the x address chain is provably scalar.
  const int wid = __builtin_amdgcn_readfirstlane((int)(threadIdx.x >> 6));

  // Load this lane's R column: Rcol[k] = R[r][k][lane]. Coalesced 256B loads,
  // L2-resident after first touch (R is 1 MB total).
  float Rcol[64];
  {
    const float* Rg = R + (size_t)r * 4096 + lane;
#pragma unroll
    for (int k = 0; k < 64; ++k) Rcol[k] = Rg[(size_t)k * 64];
  }

  const int n0 = tile * ROWS_PER_BLOCK + wid * ROWS_PER_WAVE;
  const float* __restrict__ xw = x + (size_t)n0 * 4096 + (size_t)r * 64;
  float* __restrict__ ow = out + (size_t)n0 * 4096 + (size_t)r * 64 + lane;

  for (int i = 0; i < ROWS_PER_WAVE; i += 2) {
    const float* __restrict__ xa = xw + (size_t)i * 4096;
    const float* __restrict__ xb = xa + 4096;
    float acc0 = 0.f, acc1 = 0.f;
#pragma unroll
    for (int c = 0; c < 4; ++c) {
      float a0[16], a1[16];
#pragma unroll
      for (int k = 0; k < 16; ++k) {
        a0[k] = xa[c * 16 + k];   // wave-uniform -> s_load / uniform vector load
        a1[k] = xb[c * 16 + k];
      }
#pragma unroll
      for (int k = 0; k < 16; ++k) {
        acc0 = fmaf(a0[k], Rcol[c * 16 + k], acc0);
        acc1 = fmaf(a1[k], Rcol[c * 16 + k], acc1);
      }
    }
    // Nontemporal: don't let the 134 MB output stream evict x from L3.
    __builtin_nontemporal_store(acc0, ow + (size_t)i * 4096);
    __builtin_nontemporal_store(acc1, ow + (size_t)(i + 1) * 4096);
  }
}

extern "C" void kernel_launch(void* const* d_in, const int* in_sizes, int n_in,
                              void* d_out, int out_size, void* d_ws, size_t ws_size,
                              hipStream_t stream) {
  const float* x = (const float*)d_in[0];   // (8192, 4096) fp32
  const float* w = (const float*)d_in[1];   // (64, 2016) fp32
  float* out = (float*)d_out;               // (8192, 4096) fp32
  float* Rws = (float*)d_ws;                // 64*64*64 fp32 = 1 MB scratch

  oft_build_R<<<64, 256, 0, stream>>>(w, Rws);
  oft_apply<<<dim3(64, 64), 256, 0, stream>>>(x, Rws, out);
}

// Round 2
// 261.855 us; speedup vs baseline: 1.5520x; 1.5520x over previous
//
#include <hip/hip_runtime.h>

// OFT rotation: out[n, r*64+c] = sum_k x[n, r*64+k] * R[r][k][c]
// R[r] = I + 2(Q + Q^2 + Q^3 + Q^4), Q skew-symmetric from strict-upper weights.

#define BS 64
#define NW 2016   // 64*63/2
#define LDP 68    // padded LDS row stride (build_R only)

// ---------------- Kernel 1: build R (64 blocks, one per rotation block) -------------
// UNCHANGED: known-good, bit-exact vs reference (absmax 0.0).

__device__ __forceinline__ void mm_tile_68(const float (*A)[LDP], const float (*Bm)[LDP],
                                           int r0, int c0, float p[4][4]) {
  for (int k = 0; k < 64; k += 4) {
    float4 bv[4], av[4];
#pragma unroll
    for (int u = 0; u < 4; ++u) bv[u] = *(const float4*)&Bm[k + u][c0];
#pragma unroll
    for (int i = 0; i < 4; ++i) av[i] = *(const float4*)&A[r0 + i][k];
#pragma unroll
    for (int u = 0; u < 4; ++u) {
      const float4 b = bv[u];
#pragma unroll
      for (int i = 0; i < 4; ++i) {
        const float a = ((const float*)&av[i])[u];
        p[i][0] += a * b.x;
        p[i][1] += a * b.y;
        p[i][2] += a * b.z;
        p[i][3] += a * b.w;
      }
    }
  }
}

__global__ __launch_bounds__(256) void oft_build_R(const float* __restrict__ w,
                                                   float* __restrict__ Rout) {
  const int r = blockIdx.x;
  const int t = threadIdx.x;
  __shared__ float Q[BS][LDP];
  __shared__ float Pa[BS][LDP];
  __shared__ float Pb[BS][LDP];

  for (int f = t; f < BS * LDP; f += 256) (&Q[0][0])[f] = 0.f;
  __syncthreads();

  for (int i = t; i < NW; i += 256) {
    int row = 0, rem = i;
    while (rem >= 63 - row) { rem -= 63 - row; ++row; }
    const int col = row + 1 + rem;
    const float v = w[r * NW + i];
    Q[row][col] = v;
    Q[col][row] = -v;
  }
  __syncthreads();

  const int tr = t >> 4, tc = t & 15;
  const int r0 = tr * 4, c0 = tc * 4;

  float acc[4][4];
#pragma unroll
  for (int i = 0; i < 4; ++i)
#pragma unroll
    for (int j = 0; j < 4; ++j)
      acc[i][j] = ((r0 + i) == (c0 + j) ? 1.f : 0.f) + 2.f * Q[r0 + i][c0 + j];

  float p[4][4] = {};
  mm_tile_68(Q, Q, r0, c0, p);
#pragma unroll
  for (int i = 0; i < 4; ++i)
#pragma unroll
    for (int j = 0; j < 4; ++j) {
      Pa[r0 + i][c0 + j] = p[i][j];
      acc[i][j] += 2.f * p[i][j];
    }
  __syncthreads();

  float p2[4][4] = {};
  mm_tile_68(Pa, Q, r0, c0, p2);
#pragma unroll
  for (int i = 0; i < 4; ++i)
#pragma unroll
    for (int j = 0; j < 4; ++j) {
      Pb[r0 + i][c0 + j] = p2[i][j];
      acc[i][j] += 2.f * p2[i][j];
    }
  __syncthreads();

  float p3[4][4] = {};
  mm_tile_68(Pb, Q, r0, c0, p3);
#pragma unroll
  for (int i = 0; i < 4; ++i)
#pragma unroll
    for (int j = 0; j < 4; ++j)
      acc[i][j] += 2.f * p3[i][j];

#pragma unroll
  for (int i = 0; i < 4; ++i) {
    float4 v = make_float4(acc[i][0], acc[i][1], acc[i][2], acc[i][3]);
    *(float4*)&Rout[(size_t)r * 4096 + (size_t)(r0 + i) * 64 + c0] = v;
  }
}

// ---------------- Kernel 2: apply rotation (v3: LDS-broadcast x, R in VGPRs) ---------
//
// v1 (80us): LDS-read-throughput bound, 2 B ds_read per FMA (4.3 GB LDS traffic).
// v2 (236us): wave-uniform GLOBAL loads -> zero MLP per wave, latency-bound.
// v3: coalesced global->LDS staging (32 KB/block, high MLP), then per-row
// uniform-ADDRESS ds_read_b128 broadcasts (free: same-address LDS reads
// broadcast, 16 B/instr instead of 1 KB/instr) feeding R columns held in 64
// VGPRs. LDS read volume drops ~64x vs v1 -> FMA floor (~27us) + HBM write.
// k ascends with single fma chain per output -> bit-identical to v1/reference.

#define ROWS_PER_BLOCK 128
#define ROWS_PER_WAVE 32   // 4 waves

__global__ __launch_bounds__(256) void oft_apply(const float* __restrict__ x,
                                                 const float* __restrict__ R,
                                                 float* __restrict__ out) {
  const int r = blockIdx.x;      // rotation block 0..63
  const int tile = blockIdx.y;   // row tile 0..63 (128 rows each)
  const int t = threadIdx.x;
  const int lane = t & 63;
  const int wv = t >> 6;         // 0..3

  __shared__ float Xs[ROWS_PER_BLOCK][64];   // 32 KB, no pad needed (broadcast reads)

  const int n0 = tile * ROWS_PER_BLOCK;

  // R column for this lane: Rcol[k] = R[r][k][lane]. Coalesced dword loads
  // (consecutive lanes -> consecutive addresses), L2-resident (R = 1 MB).
  // Fully unrolled, constant indices -> guaranteed VGPR-resident (rule: no
  // runtime indexing).
  float Rcol[64];
  {
    const float* Rg = R + (size_t)r * 4096 + lane;
#pragma unroll
    for (int k = 0; k < 64; ++k) Rcol[k] = Rg[(size_t)k * 64];
  }

  // Stage x tile: 128 rows x 64 cols, coalesced float4 (8 per thread).
  // ds_write aliasing is 2-way (free).
#pragma unroll
  for (int i = 0; i < 8; ++i) {
    const int f = t + 256 * i;        // 0..2047 float4 slots
    const int row = f >> 4;
    const int c4 = (f & 15) << 2;
    *(float4*)&Xs[row][c4] =
        *(const float4*)&x[(size_t)(n0 + row) * 4096 + (size_t)r * 64 + c4];
  }
  __syncthreads();

  const int row0 = wv * ROWS_PER_WAVE;
  float* __restrict__ ow = out + (size_t)(n0 + row0) * 4096 + (size_t)r * 64 + lane;

  for (int i = 0; i < ROWS_PER_WAVE; i += 2) {
    const float* xa = &Xs[row0 + i][0];        // wave-uniform address
    const float* xb = &Xs[row0 + i + 1][0];
    float acc0 = 0.f, acc1 = 0.f;
#pragma unroll
    for (int k4 = 0; k4 < 16; ++k4) {
      const float4 a = *(const float4*)&xa[k4 * 4];   // ds_read_b128 broadcast
      const float4 b = *(const float4*)&xb[k4 * 4];
      acc0 = fmaf(a.x, Rcol[k4 * 4 + 0], acc0);
      acc0 = fmaf(a.y, Rcol[k4 * 4 + 1], acc0);
      acc0 = fmaf(a.z, Rcol[k4 * 4 + 2], acc0);
      acc0 = fmaf(a.w, Rcol[k4 * 4 + 3], acc0);
      acc1 = fmaf(b.x, Rcol[k4 * 4 + 0], acc1);
      acc1 = fmaf(b.y, Rcol[k4 * 4 + 1], acc1);
      acc1 = fmaf(b.z, Rcol[k4 * 4 + 2], acc1);
      acc1 = fmaf(b.w, Rcol[k4 * 4 + 3], acc1);
    }
    // nt stores: keep the 134 MB output stream out of L3 so x stays resident
    // (v2 counters confirmed: FETCH ~0 passes with nt stores).
    __builtin_nontemporal_store(acc0, ow + (size_t)i * 4096);
    __builtin_nontemporal_store(acc1, ow + (size_t)(i + 1) * 4096);
  }
}

extern "C" void kernel_launch(void* const* d_in, const int* in_sizes, int n_in,
                              void* d_out, int out_size, void* d_ws, size_t ws_size,
                              hipStream_t stream) {
  const float* x = (const float*)d_in[0];   // (8192, 4096) fp32
  const float* w = (const float*)d_in[1];   // (64, 2016) fp32
  float* out = (float*)d_out;               // (8192, 4096) fp32
  float* Rws = (float*)d_ws;                // 64*64*64 fp32 = 1 MB scratch

  oft_build_R<<<64, 256, 0, stream>>>(w, Rws);
  oft_apply<<<dim3(64, 64), 256, 0, stream>>>(x, Rws, out);
}